// Round 5
// baseline (2032.877 us; speedup 1.0000x reference)
//
#include <hip/hip_runtime.h>

typedef unsigned short u16;
typedef __attribute__((ext_vector_type(8))) short short8;
typedef __attribute__((ext_vector_type(4))) float f32x4;

constexpr int SA     = 168;   // act row stride (bf16): 336 B -> 2-way banks (free)
constexpr int BLK_E  = 96;    // edges per block
constexpr int NTHR   = 128;   // 2 waves, each owns 48 edges x full N
constexpr int MT     = 3;     // M-tiles per wave (48 edges)
constexpr int J_MAX  = 10;    // N tiles (160 padded)
constexpr int KS_MAX = 5;     // K steps of 32 (160 padded)
constexpr int CHUNK  = 512;   // elems per (j,ks) fragment chunk = 1 KB
constexpr int WSLOT  = J_MAX * KS_MAX * CHUNK;   // 25600 elems = 51200 B / layer

__device__ __forceinline__ u16 f2bf(float f) {  // RNE f32->bf16
    union { float f; unsigned u; } c; c.f = f;
    return (u16)((c.u + 0x7fffu + ((c.u >> 16) & 1u)) >> 16);
}

// activation k-storage permutation (hidden layers):
//  logical n = j*16+col stored at k' = col*8+j (j<8) | 128+col*2+(j-8) (j=8,9)
__device__ __forceinline__ int kperm(int kp) {
    if (kp < 128) return (kp & 7) * 16 + (kp >> 3);
    if (kp < 160) { const int m = kp - 128; return (8 + (m & 1)) * 16 + (m >> 1); }
    return 1 << 30;
}

// ---- prep: weights -> MFMA fragment order ----------------------------------
// chunk(j,ks) = 1 KB: lane l (= q*16+c), elems e=0..7 hold
//   W^T[n = j*16+c][kphys = ks*32 + q*8 + e]   (kphys permuted for hidden layers)
__global__ void prep_weights(const float* __restrict__ W0, const float* __restrict__ W1,
                             const float* __restrict__ W2, const float* __restrict__ W3,
                             const float* __restrict__ W4, u16* __restrict__ out)
{
    const int l = blockIdx.y;
    const float* W; int DI, DO; bool perm;
    if      (l == 0) { W = W0; DI = 13;  DO = 150; perm = false; }
    else if (l == 1) { W = W1; DI = 150; DO = 150; perm = true;  }
    else if (l == 2) { W = W2; DI = 150; DO = 150; perm = true;  }
    else if (l == 3) { W = W3; DI = 150; DO = 150; perm = true;  }
    else             { W = W4; DI = 150; DO = 50;  perm = true;  }
    u16* dst = out + (size_t)l * WSLOT;
    for (int idx = blockIdx.x * blockDim.x + threadIdx.x; idx < WSLOT;
         idx += gridDim.x * blockDim.x) {
        const int chunk = idx / CHUNK;
        const int within = idx - chunk * CHUNK;
        const int lane = within >> 3, e = within & 7;
        const int j = chunk / KS_MAX, ks = chunk - j * KS_MAX;
        const int c = lane & 15, q = lane >> 4;
        const int n = j * 16 + c;
        const int kphys = ks * 32 + q * 8 + e;
        const int klog = perm ? kperm(kphys) : kphys;
        const float v = (n < DO && klog < DI) ? W[klog * DO + n] : 0.f;
        dst[idx] = f2bf(v);
    }
}

// ---- one MLP layer: A from LDS (wave-private rows), B coalesced from L2 ----
// B consumed in halves of NH to keep live VGPRs under the (128,3) cap.
template<int KS, int NT, int NH>
__device__ __forceinline__ void gemm_layer(
    const u16* __restrict__ Wl, const u16* actw,
    int lane, int col, int quad, f32x4 (&acc)[MT][NT])
{
#pragma unroll
    for (int i = 0; i < MT; ++i)
#pragma unroll
        for (int j = 0; j < NT; ++j)
            acc[i][j] = f32x4{0.f, 0.f, 0.f, 0.f};

    const u16* wbase = Wl + lane * 8;   // lane's 16B within each 1 KB chunk
#pragma unroll
    for (int ks = 0; ks < KS; ++ks) {
        const int koff = ks * 32 + quad * 8;
        short8 Af[MT];
#pragma unroll
        for (int i = 0; i < MT; ++i)
            Af[i] = *(const short8*)&actw[(i * 16 + col) * SA + koff];
#pragma unroll
        for (int h = 0; h < NT; h += NH) {
            short8 Bf[NH];
#pragma unroll
            for (int jj = 0; jj < NH; ++jj)
                Bf[jj] = *(const short8*)&wbase[((h + jj) * KS_MAX + ks) * CHUNK];
#pragma unroll
            for (int jj = 0; jj < NH; ++jj)
#pragma unroll
                for (int i = 0; i < MT; ++i)
                    acc[i][h + jj] = __builtin_amdgcn_mfma_f32_16x16x32_bf16(
                        Af[i], Bf[jj], acc[i][h + jj], 0, 0, 0);
        }
    }
}

// ---- epilogue: bias+relu+bf16, k-permuted in-place store (b128 + b32) ------
__device__ __forceinline__ void epilogue(
    u16* actw, const float* __restrict__ bias,
    int col, int quad, f32x4 (&acc)[MT][10])
{
    float bb[10];
#pragma unroll
    for (int j = 0; j < 10; ++j) {
        const int n = j * 16 + col;
        bb[j] = (n < 150) ? bias[n] : 0.f;
    }
#pragma unroll
    for (int i = 0; i < MT; ++i)
#pragma unroll
        for (int r = 0; r < 4; ++r) {
            u16* row = &actw[(i * 16 + quad * 4 + r) * SA];
            short8 pk;
#pragma unroll
            for (int j = 0; j < 8; ++j)
                pk[j] = (short)f2bf(fmaxf(acc[i][j][r] + bb[j], 0.f));
            *(short8*)&row[col * 8] = pk;                         // k' = col*8 + j
            const u16 lo = f2bf(fmaxf(acc[i][8][r] + bb[8], 0.f));
            const u16 hi = f2bf(fmaxf(acc[i][9][r] + bb[9], 0.f));
            *(unsigned*)&row[128 + col * 2] =                      // k' = 128+col*2+(j-8)
                (unsigned)lo | ((unsigned)hi << 16);
        }
}

// ------------------------------- Edge kernel --------------------------------
// ZERO barriers: each wave owns edges [wv*48, wv*48+48) — gather, A-reads and
// epilogue writes all touch only that slab. 32640 B LDS -> 5 blocks/CU.
__global__ __launch_bounds__(NTHR, 3) void edge_kernel(
    const float* __restrict__ t, const float* __restrict__ x, const float* __restrict__ Ofx,
    const int* __restrict__ src, const int* __restrict__ tgt,
    const u16* __restrict__ Wt,
    const float* __restrict__ B0, const float* __restrict__ B1, const float* __restrict__ B2,
    const float* __restrict__ B3, const float* __restrict__ B4,
    float* __restrict__ Ep, int n_edges)
{
    __shared__ __align__(16) u16 act[BLK_E * SA];    // 32256 B
    __shared__ int tgt_s[BLK_E];                     // 384 B

    const int tid  = threadIdx.x;
    const int lane = tid & 63;
    const int wv   = tid >> 6;
    const int col  = lane & 15;
    const int quad = lane >> 4;

    // ---- gather R' (wave-private rows), packed b128 LDS writes ----
    if (lane < 48) {
        const int e = wv * 48 + lane;
        const long long ge = (long long)blockIdx.x * BLK_E + e;
        const bool valid = ge < n_edges;
        const int s = valid ? src[ge] : 0;
        const int g = valid ? tgt[ge] : 0;
        float v[16];
        const float4 xs = valid ? *(const float4*)&x[(size_t)s * 4] : float4{0, 0, 0, 0};
        const float2 os = valid ? *(const float2*)&Ofx[(size_t)s * 2] : float2{0, 0};
        const float4 xg = valid ? *(const float4*)&x[(size_t)g * 4] : float4{0, 0, 0, 0};
        const float2 og = valid ? *(const float2*)&Ofx[(size_t)g * 2] : float2{0, 0};
        v[0] = xs.x; v[1] = xs.y; v[2] = xs.z; v[3] = xs.w; v[4] = os.x; v[5] = os.y;
        v[6] = xg.x; v[7] = xg.y; v[8] = xg.z; v[9] = xg.w; v[10] = og.x; v[11] = og.y;
        v[12] = valid ? t[0] : 0.f; v[13] = v[14] = v[15] = 0.f;
        short8 c0, c1;
#pragma unroll
        for (int k = 0; k < 8; ++k) { c0[k] = (short)f2bf(v[k]); c1[k] = (short)f2bf(v[k + 8]); }
        u16* row = &act[e * SA];
        *(short8*)&row[0]  = c0;
        *(short8*)&row[8]  = c1;
        *(short8*)&row[16] = short8{0, 0, 0, 0, 0, 0, 0, 0};
        *(short8*)&row[24] = short8{0, 0, 0, 0, 0, 0, 0, 0};
        tgt_s[e] = valid ? g : -1;
    }
    // no __syncthreads: all later accesses are wave-private (lgkmcnt orders them)

    u16* actw = act + wv * 48 * SA;
    f32x4 acc[MT][10];

    gemm_layer<1, 10, 5>(Wt + 0 * WSLOT, actw, lane, col, quad, acc);   // L0: K=32(13)
    epilogue(actw, B0, col, quad, acc);
    gemm_layer<5, 10, 5>(Wt + 1 * WSLOT, actw, lane, col, quad, acc);   // L1
    epilogue(actw, B1, col, quad, acc);
    gemm_layer<5, 10, 5>(Wt + 2 * WSLOT, actw, lane, col, quad, acc);   // L2
    epilogue(actw, B2, col, quad, acc);
    gemm_layer<5, 10, 5>(Wt + 3 * WSLOT, actw, lane, col, quad, acc);   // L3
    epilogue(actw, B3, col, quad, acc);

    f32x4 acc4[MT][4];
    gemm_layer<5, 4, 4>(Wt + 4 * WSLOT, actw, lane, col, quad, acc4);   // L4: ->50(64)

    // ---- scatter-add E into Ep[tgt][50]: 4 nodes x 64 B per instruction ----
#pragma unroll
    for (int j = 0; j < 4; ++j) {
        const int n = j * 16 + col;
        if (n < 50) {
            const float bb = B4[n];
#pragma unroll
            for (int i = 0; i < MT; ++i)
#pragma unroll
                for (int r = 0; r < 4; ++r) {
                    const int g = tgt_s[wv * 48 + i * 16 + quad * 4 + r];
                    if (g >= 0) atomicAdd(&Ep[(size_t)g * 50 + n], acc4[i][j][r] + bb);
                }
        }
    }
}

// ---------------- Node kernel (fp32 VALU — small cost) ----------------------
template<int DI, int DO, bool RELU>
__device__ __forceinline__ void mlp_layer_t(
    const float* __restrict__ W, const float* __restrict__ B,
    float (*in)[64], float (*out)[64], int tid)
{
    const int et = tid & 15;
    const int jt = tid >> 4;
    constexpr int NG = (DO + 15) / 16;

    float acc0[NG], acc1[NG], acc2[NG], acc3[NG];
#pragma unroll
    for (int g = 0; g < NG; ++g) {
        const int j = jt + 16 * g;
        const float bb = (j < DO) ? B[j] : 0.f;
        acc0[g] = bb; acc1[g] = bb; acc2[g] = bb; acc3[g] = bb;
    }
    for (int k = 0; k < DI; ++k) {
        const float4 a = *(const float4*)&in[k][et * 4];
#pragma unroll
        for (int g = 0; g < NG; ++g) {
            const int j = jt + 16 * g;
            const float wv = (j < DO) ? W[k * DO + j] : 0.f;
            acc0[g] = fmaf(a.x, wv, acc0[g]);
            acc1[g] = fmaf(a.y, wv, acc1[g]);
            acc2[g] = fmaf(a.z, wv, acc2[g]);
            acc3[g] = fmaf(a.w, wv, acc3[g]);
        }
    }
#pragma unroll
    for (int g = 0; g < NG; ++g) {
        const int j = jt + 16 * g;
        if (j < DO) {
            float4 v; v.x = acc0[g]; v.y = acc1[g]; v.z = acc2[g]; v.w = acc3[g];
            if (RELU) {
                v.x = fmaxf(v.x, 0.f); v.y = fmaxf(v.y, 0.f);
                v.z = fmaxf(v.z, 0.f); v.w = fmaxf(v.w, 0.f);
            }
            *(float4*)&out[j][et * 4] = v;
        }
    }
}

__global__ __launch_bounds__(256, 2) void node_kernel(
    const float* __restrict__ Eprime,
    const float* __restrict__ W0, const float* __restrict__ B0,
    const float* __restrict__ W1, const float* __restrict__ B1,
    float* __restrict__ P, int n_nodes)
{
    __shared__ float bufA[104][64];
    __shared__ float bufB[104][64];
    const int tid = threadIdx.x;
    const int n0  = blockIdx.x * 64;

    for (int idx = tid; idx < 64 * 50; idx += 256) {
        const int e = idx / 50;
        const int k = idx - e * 50;
        const int n = n0 + e;
        bufA[k][e] = (n < n_nodes) ? Eprime[(size_t)n * 50 + k] : 0.f;
    }
    __syncthreads();
    mlp_layer_t<50, 100, true >(W0, B0, bufA, bufB, tid); __syncthreads();
    mlp_layer_t<100, 4, false>(W1, B1, bufB, bufA, tid); __syncthreads();
    for (int idx = tid; idx < 64 * 4; idx += 256) {
        const int e = idx & 63;
        const int j = idx >> 6;
        const int n = n0 + e;
        if (n < n_nodes) P[(size_t)n * 4 + j] = bufA[j][e];
    }
}

// ------------------------------- launcher -----------------------------------
extern "C" void kernel_launch(void* const* d_in, const int* in_sizes, int n_in,
                              void* d_out, int out_size, void* d_ws, size_t ws_size,
                              hipStream_t stream)
{
    const float* t   = (const float*)d_in[0];
    const float* x   = (const float*)d_in[1];
    const float* Ofx = (const float*)d_in[2];
    const int*   src = (const int*)d_in[3];
    const int*   tgt = (const int*)d_in[4];
    const float* W0  = (const float*)d_in[5];  const float* B0 = (const float*)d_in[6];
    const float* W1  = (const float*)d_in[7];  const float* B1 = (const float*)d_in[8];
    const float* W2  = (const float*)d_in[9];  const float* B2 = (const float*)d_in[10];
    const float* W3  = (const float*)d_in[11]; const float* B3 = (const float*)d_in[12];
    const float* W4  = (const float*)d_in[13]; const float* B4 = (const float*)d_in[14];
    const float* OW0 = (const float*)d_in[15]; const float* OB0 = (const float*)d_in[16];
    const float* OW1 = (const float*)d_in[17]; const float* OB1 = (const float*)d_in[18];

    const int n_nodes = in_sizes[1] / 4;
    const int n_edges = in_sizes[3];

    float* Ep = (float*)d_ws;                                               // [N,50] fp32
    u16*   Wt = (u16*)((char*)d_ws + (size_t)n_nodes * 50 * sizeof(float)); // 5 x 51.2 KB

    prep_weights<<<dim3(32, 5), 256, 0, stream>>>(W0, W1, W2, W3, W4, Wt);
    hipMemsetAsync(Ep, 0, (size_t)n_nodes * 50 * sizeof(float), stream);

    edge_kernel<<<(n_edges + BLK_E - 1) / BLK_E, NTHR, 0, stream>>>(
        t, x, Ofx, src, tgt, Wt, B0, B1, B2, B3, B4, Ep, n_edges);

    node_kernel<<<(n_nodes + 63) / 64, 256, 0, stream>>>(
        Ep, OW0, OB0, OW1, OB1, (float*)d_out, n_nodes);
}

// Round 6
// 1709.573 us; speedup vs baseline: 1.1891x; 1.1891x over previous
//
#include <hip/hip_runtime.h>

typedef unsigned short u16;
typedef __attribute__((ext_vector_type(8))) short short8;
typedef __attribute__((ext_vector_type(4))) float f32x4;

constexpr int SA     = 168;   // act row stride (bf16): 336 B -> 2-way banks (free)
constexpr int BLK_E  = 128;   // edges per block
constexpr int NTHR   = 128;   // 2 waves, each owns 64 edges x full N
constexpr int MT     = 4;     // M-tiles per wave (64 edges)
constexpr int J_MAX  = 10;    // N tiles (160 padded)
constexpr int KS_MAX = 5;     // K steps of 32 (160 padded)
constexpr int CHUNK  = 512;   // elems per (j,ks) fragment chunk = 1 KB
constexpr int WSLOT  = J_MAX * KS_MAX * CHUNK;   // 25600 elems = 51200 B / layer

__device__ __forceinline__ u16 f2bf(float f) {  // RNE f32->bf16
    union { float f; unsigned u; } c; c.f = f;
    return (u16)((c.u + 0x7fffu + ((c.u >> 16) & 1u)) >> 16);
}

// activation k-storage permutation (hidden layers):
//  logical n = j*16+col stored at k' = col*8+j (j<8) | 128+col*2+(j-8) (j=8,9)
__device__ __forceinline__ int kperm(int kp) {
    if (kp < 128) return (kp & 7) * 16 + (kp >> 3);
    if (kp < 160) { const int m = kp - 128; return (8 + (m & 1)) * 16 + (m >> 1); }
    return 1 << 30;
}

// ---- prep: weights -> MFMA fragment order ----------------------------------
__global__ void prep_weights(const float* __restrict__ W0, const float* __restrict__ W1,
                             const float* __restrict__ W2, const float* __restrict__ W3,
                             const float* __restrict__ W4, u16* __restrict__ out)
{
    const int l = blockIdx.y;
    const float* W; int DI, DO; bool perm;
    if      (l == 0) { W = W0; DI = 13;  DO = 150; perm = false; }
    else if (l == 1) { W = W1; DI = 150; DO = 150; perm = true;  }
    else if (l == 2) { W = W2; DI = 150; DO = 150; perm = true;  }
    else if (l == 3) { W = W3; DI = 150; DO = 150; perm = true;  }
    else             { W = W4; DI = 150; DO = 50;  perm = true;  }
    u16* dst = out + (size_t)l * WSLOT;
    for (int idx = blockIdx.x * blockDim.x + threadIdx.x; idx < WSLOT;
         idx += gridDim.x * blockDim.x) {
        const int chunk = idx / CHUNK;
        const int within = idx - chunk * CHUNK;
        const int lane = within >> 3, e = within & 7;
        const int j = chunk / KS_MAX, ks = chunk - j * KS_MAX;
        const int c = lane & 15, q = lane >> 4;
        const int n = j * 16 + c;
        const int kphys = ks * 32 + q * 8 + e;
        const int klog = perm ? kperm(kphys) : kphys;
        const float v = (n < DO && klog < DI) ? W[klog * DO + n] : 0.f;
        dst[idx] = f2bf(v);
    }
}

// ---- one MLP layer: A from LDS (wave-private rows), B coalesced from L2 ----
template<int KS, int NT>
__device__ __forceinline__ void gemm_layer(
    const u16* __restrict__ Wl, const u16* actw,
    int lane, int col, int quad, f32x4 (&acc)[MT][NT])
{
#pragma unroll
    for (int i = 0; i < MT; ++i)
#pragma unroll
        for (int j = 0; j < NT; ++j)
            acc[i][j] = f32x4{0.f, 0.f, 0.f, 0.f};

    const u16* wbase = Wl + lane * 8;   // lane's 16B within each 1 KB chunk
#pragma unroll
    for (int ks = 0; ks < KS; ++ks) {
        const int koff = ks * 32 + quad * 8;
        short8 Af[MT];
#pragma unroll
        for (int i = 0; i < MT; ++i)
            Af[i] = *(const short8*)&actw[(i * 16 + col) * SA + koff];
#pragma unroll
        for (int j = 0; j < NT; ++j) {
            const short8 Bf = *(const short8*)&wbase[(j * KS_MAX + ks) * CHUNK];
#pragma unroll
            for (int i = 0; i < MT; ++i)
                acc[i][j] = __builtin_amdgcn_mfma_f32_16x16x32_bf16(Af[i], Bf, acc[i][j], 0, 0, 0);
        }
    }
}

// ---- epilogue: bias+relu+bf16, k-permuted in-place store (b128 + b32) ------
__device__ __forceinline__ void epilogue(
    u16* actw, const float* __restrict__ bias,
    int col, int quad, f32x4 (&acc)[MT][10])
{
    float bb[10];
#pragma unroll
    for (int j = 0; j < 10; ++j) {
        const int n = j * 16 + col;
        bb[j] = (n < 150) ? bias[n] : 0.f;
    }
#pragma unroll
    for (int i = 0; i < MT; ++i)
#pragma unroll
        for (int r = 0; r < 4; ++r) {
            u16* row = &actw[(i * 16 + quad * 4 + r) * SA];
            short8 pk;
#pragma unroll
            for (int j = 0; j < 8; ++j)
                pk[j] = (short)f2bf(fmaxf(acc[i][j][r] + bb[j], 0.f));
            *(short8*)&row[col * 8] = pk;                         // k' = col*8 + j
            const u16 lo = f2bf(fmaxf(acc[i][8][r] + bb[8], 0.f));
            const u16 hi = f2bf(fmaxf(acc[i][9][r] + bb[9], 0.f));
            *(unsigned*)&row[128 + col * 2] =                      // k' = 128+col*2+(j-8)
                (unsigned)lo | ((unsigned)hi << 16);
        }
}

// ------------------------------- Edge kernel --------------------------------
// ZERO barriers; scatter goes to this XCD's private Ep copy (no cross-XCD
// line ping-pong). Any xcd value in [0,ncopies) is correct — it's a partition.
__global__ __launch_bounds__(NTHR, 2) void edge_kernel(
    const float* __restrict__ t, const float* __restrict__ x, const float* __restrict__ Ofx,
    const int* __restrict__ src, const int* __restrict__ tgt,
    const u16* __restrict__ Wt,
    const float* __restrict__ B0, const float* __restrict__ B1, const float* __restrict__ B2,
    const float* __restrict__ B3, const float* __restrict__ B4,
    float* __restrict__ Ep, int n_edges, int copy_mask, size_t copy_elems)
{
    __shared__ __align__(16) u16 act[BLK_E * SA];    // 43008 B -> 3 blocks/CU
    __shared__ int tgt_s[BLK_E];

    const int tid  = threadIdx.x;
    const int lane = tid & 63;
    const int wv   = tid >> 6;
    const int col  = lane & 15;
    const int quad = lane >> 4;

    // physical XCD id (gfx950 HW_REG_XCC_ID=20, offset 0, width 4 -> imm 6164)
    const int xcd = (int)(__builtin_amdgcn_s_getreg(6164) & 7u) & copy_mask;
    float* __restrict__ Epc = Ep + (size_t)xcd * copy_elems;

    // ---- gather R' (wave-private rows), packed b128 LDS writes ----
    {
        const int e = tid;
        const long long ge = (long long)blockIdx.x * BLK_E + e;
        const bool valid = ge < n_edges;
        const int s = valid ? src[ge] : 0;
        const int g = valid ? tgt[ge] : 0;
        float v[16];
        const float4 xs = valid ? *(const float4*)&x[(size_t)s * 4] : float4{0, 0, 0, 0};
        const float2 os = valid ? *(const float2*)&Ofx[(size_t)s * 2] : float2{0, 0};
        const float4 xg = valid ? *(const float4*)&x[(size_t)g * 4] : float4{0, 0, 0, 0};
        const float2 og = valid ? *(const float2*)&Ofx[(size_t)g * 2] : float2{0, 0};
        v[0] = xs.x; v[1] = xs.y; v[2] = xs.z; v[3] = xs.w; v[4] = os.x; v[5] = os.y;
        v[6] = xg.x; v[7] = xg.y; v[8] = xg.z; v[9] = xg.w; v[10] = og.x; v[11] = og.y;
        v[12] = valid ? t[0] : 0.f; v[13] = v[14] = v[15] = 0.f;
        short8 c0, c1;
#pragma unroll
        for (int k = 0; k < 8; ++k) { c0[k] = (short)f2bf(v[k]); c1[k] = (short)f2bf(v[k + 8]); }
        u16* row = &act[e * SA];
        *(short8*)&row[0]  = c0;
        *(short8*)&row[8]  = c1;
        *(short8*)&row[16] = short8{0, 0, 0, 0, 0, 0, 0, 0};
        *(short8*)&row[24] = short8{0, 0, 0, 0, 0, 0, 0, 0};
        tgt_s[e] = valid ? g : -1;
    }
    // no __syncthreads: all later accesses are wave-private (lgkmcnt orders them)

    u16* actw = act + wv * 64 * SA;
    f32x4 acc[MT][10];

    gemm_layer<1, 10>(Wt + 0 * WSLOT, actw, lane, col, quad, acc);   // L0: K=32(13)
    epilogue(actw, B0, col, quad, acc);
    gemm_layer<5, 10>(Wt + 1 * WSLOT, actw, lane, col, quad, acc);   // L1
    epilogue(actw, B1, col, quad, acc);
    gemm_layer<5, 10>(Wt + 2 * WSLOT, actw, lane, col, quad, acc);   // L2
    epilogue(actw, B2, col, quad, acc);
    gemm_layer<5, 10>(Wt + 3 * WSLOT, actw, lane, col, quad, acc);   // L3
    epilogue(actw, B3, col, quad, acc);

    f32x4 acc4[MT][4];
    gemm_layer<5, 4>(Wt + 4 * WSLOT, actw, lane, col, quad, acc4);   // L4: ->50(64)

    // ---- scatter-add E into XCD-local Ep copy ----
#pragma unroll
    for (int j = 0; j < 4; ++j) {
        const int n = j * 16 + col;
        if (n < 50) {
            const float bb = B4[n];
#pragma unroll
            for (int i = 0; i < MT; ++i)
#pragma unroll
                for (int r = 0; r < 4; ++r) {
                    const int g = tgt_s[wv * 64 + i * 16 + quad * 4 + r];
                    if (g >= 0) atomicAdd(&Epc[(size_t)g * 50 + n], acc4[i][j][r] + bb);
                }
        }
    }
}

// ---------------- Node kernel: reduce copies + fO MLP (fp32 VALU) -----------
template<int DI, int DO, bool RELU>
__device__ __forceinline__ void mlp_layer_t(
    const float* __restrict__ W, const float* __restrict__ B,
    float (*in)[64], float (*out)[64], int tid)
{
    const int et = tid & 15;
    const int jt = tid >> 4;
    constexpr int NG = (DO + 15) / 16;

    float acc0[NG], acc1[NG], acc2[NG], acc3[NG];
#pragma unroll
    for (int g = 0; g < NG; ++g) {
        const int j = jt + 16 * g;
        const float bb = (j < DO) ? B[j] : 0.f;
        acc0[g] = bb; acc1[g] = bb; acc2[g] = bb; acc3[g] = bb;
    }
    for (int k = 0; k < DI; ++k) {
        const float4 a = *(const float4*)&in[k][et * 4];
#pragma unroll
        for (int g = 0; g < NG; ++g) {
            const int j = jt + 16 * g;
            const float wv = (j < DO) ? W[k * DO + j] : 0.f;
            acc0[g] = fmaf(a.x, wv, acc0[g]);
            acc1[g] = fmaf(a.y, wv, acc1[g]);
            acc2[g] = fmaf(a.z, wv, acc2[g]);
            acc3[g] = fmaf(a.w, wv, acc3[g]);
        }
    }
#pragma unroll
    for (int g = 0; g < NG; ++g) {
        const int j = jt + 16 * g;
        if (j < DO) {
            float4 v; v.x = acc0[g]; v.y = acc1[g]; v.z = acc2[g]; v.w = acc3[g];
            if (RELU) {
                v.x = fmaxf(v.x, 0.f); v.y = fmaxf(v.y, 0.f);
                v.z = fmaxf(v.z, 0.f); v.w = fmaxf(v.w, 0.f);
            }
            *(float4*)&out[j][et * 4] = v;
        }
    }
}

__global__ __launch_bounds__(256, 2) void node_kernel(
    const float* __restrict__ Ep, int ncopies, size_t copy_elems,
    const float* __restrict__ W0, const float* __restrict__ B0,
    const float* __restrict__ W1, const float* __restrict__ B1,
    float* __restrict__ P, int n_nodes)
{
    __shared__ float bufA[104][64];
    __shared__ float bufB[104][64];
    const int tid = threadIdx.x;
    const int n0  = blockIdx.x * 64;

    for (int idx = tid; idx < 64 * 50; idx += 256) {
        const int e = idx / 50;
        const int k = idx - e * 50;
        const int n = n0 + e;
        float s = 0.f;
        if (n < n_nodes) {
            const float* p = &Ep[(size_t)n * 50 + k];
            for (int c = 0; c < ncopies; ++c) s += p[(size_t)c * copy_elems];
        }
        bufA[k][e] = s;
    }
    __syncthreads();
    mlp_layer_t<50, 100, true >(W0, B0, bufA, bufB, tid); __syncthreads();
    mlp_layer_t<100, 4, false>(W1, B1, bufB, bufA, tid); __syncthreads();
    for (int idx = tid; idx < 64 * 4; idx += 256) {
        const int e = idx & 63;
        const int j = idx >> 6;
        const int n = n0 + e;
        if (n < n_nodes) P[(size_t)n * 4 + j] = bufA[j][e];
    }
}

// ------------------------------- launcher -----------------------------------
extern "C" void kernel_launch(void* const* d_in, const int* in_sizes, int n_in,
                              void* d_out, int out_size, void* d_ws, size_t ws_size,
                              hipStream_t stream)
{
    const float* t   = (const float*)d_in[0];
    const float* x   = (const float*)d_in[1];
    const float* Ofx = (const float*)d_in[2];
    const int*   src = (const int*)d_in[3];
    const int*   tgt = (const int*)d_in[4];
    const float* W0  = (const float*)d_in[5];  const float* B0 = (const float*)d_in[6];
    const float* W1  = (const float*)d_in[7];  const float* B1 = (const float*)d_in[8];
    const float* W2  = (const float*)d_in[9];  const float* B2 = (const float*)d_in[10];
    const float* W3  = (const float*)d_in[11]; const float* B3 = (const float*)d_in[12];
    const float* W4  = (const float*)d_in[13]; const float* B4 = (const float*)d_in[14];
    const float* OW0 = (const float*)d_in[15]; const float* OB0 = (const float*)d_in[16];
    const float* OW1 = (const float*)d_in[17]; const float* OB1 = (const float*)d_in[18];

    const int n_nodes = in_sizes[1] / 4;
    const int n_edges = in_sizes[3];

    u16*   Wt = (u16*)d_ws;                                // 256000 B
    float* Ep = (float*)((char*)d_ws + 262144);            // ncopies x [N,50] fp32

    const size_t copy_elems = (size_t)n_nodes * 50;
    const size_t avail = (ws_size > 262144) ? ws_size - 262144 : 0;
    int ncopies = 1;                                        // power of two, <= 8
    while (ncopies * 2 <= 8 &&
           (size_t)(ncopies * 2) * copy_elems * sizeof(float) <= avail)
        ncopies *= 2;
    const int copy_mask = ncopies - 1;

    prep_weights<<<dim3(32, 5), 256, 0, stream>>>(W0, W1, W2, W3, W4, Wt);
    hipMemsetAsync(Ep, 0, (size_t)ncopies * copy_elems * sizeof(float), stream);

    edge_kernel<<<(n_edges + BLK_E - 1) / BLK_E, NTHR, 0, stream>>>(
        t, x, Ofx, src, tgt, Wt, B0, B1, B2, B3, B4,
        Ep, n_edges, copy_mask, copy_elems);

    node_kernel<<<(n_nodes + 63) / 64, 256, 0, stream>>>(
        Ep, ncopies, copy_elems, OW0, OB0, OW1, OB1, (float*)d_out, n_nodes);
}

// Round 7
// 1159.743 us; speedup vs baseline: 1.7529x; 1.4741x over previous
//
#include <hip/hip_runtime.h>

typedef unsigned short u16;
typedef __attribute__((ext_vector_type(8))) short short8;
typedef __attribute__((ext_vector_type(4))) float f32x4;

constexpr int SA     = 168;   // act row stride (bf16): 336 B, 16B-aligned
constexpr int BLK_E  = 128;   // edges per block
constexpr int NTHR   = 256;   // 4 waves, each owns 32 edges (MT=2)
constexpr int J_MAX  = 10;    // N tiles (160 padded)
constexpr int KS_MAX = 5;     // K slices of 32 (160 padded)
constexpr int CHUNK  = 512;   // u16 elems per (j) fragment chunk = 1 KB
constexpr int NCHB   = 12;    // chunks per LDS slice buffer (10 real + 2 dummy)
constexpr int BUFSZ  = NCHB * CHUNK;             // 6144 elems per buffer
constexpr int SLICE_G = J_MAX * CHUNK;           // 5120 elems per global slice
constexpr int WSLOT  = KS_MAX * SLICE_G;         // 25600 elems per layer

typedef __attribute__((address_space(1))) const unsigned int gu32;
typedef __attribute__((address_space(3))) unsigned int lu32;

__device__ __forceinline__ void gload_lds16(const u16* g, u16* l) {
    // 16B per lane; LDS dest = wave-uniform base + lane*16 (HW scatter)
    __builtin_amdgcn_global_load_lds((gu32*)g, (lu32*)l, 16, 0, 0);
}

__device__ __forceinline__ u16 f2bf(float f) {  // RNE f32->bf16
    union { float f; unsigned u; } c; c.f = f;
    return (u16)((c.u + 0x7fffu + ((c.u >> 16) & 1u)) >> 16);
}

// activation k-storage permutation (hidden layers):
//  logical n = j*16+col stored at k' = col*8+j (j<8) | 128+col*2+(j-8) (j=8,9)
__device__ __forceinline__ int kperm(int kp) {
    if (kp < 128) return (kp & 7) * 16 + (kp >> 3);
    if (kp < 160) { const int m = kp - 128; return (8 + (m & 1)) * 16 + (m >> 1); }
    return 1 << 30;
}

// ---- prep: weights -> slice-major MFMA fragment order ----------------------
// layer slot: [ks][j][lane][e]: lane l (= q*16+c), e=0..7 holds
//   W^T[n = j*16+c][kphys = ks*32 + q*8 + e]  (kphys permuted for hidden layers)
__global__ void prep_weights(const float* __restrict__ W0, const float* __restrict__ W1,
                             const float* __restrict__ W2, const float* __restrict__ W3,
                             const float* __restrict__ W4, u16* __restrict__ out)
{
    const int l = blockIdx.y;
    const float* W; int DI, DO; bool perm;
    if      (l == 0) { W = W0; DI = 13;  DO = 150; perm = false; }
    else if (l == 1) { W = W1; DI = 150; DO = 150; perm = true;  }
    else if (l == 2) { W = W2; DI = 150; DO = 150; perm = true;  }
    else if (l == 3) { W = W3; DI = 150; DO = 150; perm = true;  }
    else             { W = W4; DI = 150; DO = 50;  perm = true;  }
    u16* dst = out + (size_t)l * WSLOT;
    for (int idx = blockIdx.x * blockDim.x + threadIdx.x; idx < WSLOT;
         idx += gridDim.x * blockDim.x) {
        const int chunk = idx / CHUNK;            // = ks*J_MAX + j
        const int within = idx - chunk * CHUNK;
        const int lane = within >> 3, e = within & 7;
        const int ks = chunk / J_MAX, j = chunk - ks * J_MAX;
        const int c = lane & 15, q = lane >> 4;
        const int n = j * 16 + c;
        const int kphys = ks * 32 + q * 8 + e;
        const int klog = perm ? kperm(kphys) : kphys;
        const float v = (n < DO && klog < DI) ? W[klog * DO + n] : 0.f;
        dst[idx] = f2bf(v);
    }
}

// ---- async stage one 10-chunk slice into a 12-chunk LDS buffer -------------
__device__ __forceinline__ void stage_slice(const u16* __restrict__ gslice,
                                            u16* lbuf, int wv, int lane) {
#pragma unroll
    for (int k = 0; k < 3; ++k) {
        const int c  = wv * 3 + k;                 // 0..11 across 4 waves
        const int c2 = (c < J_MAX) ? c : (c - J_MAX);   // dummies re-read 0,1
        gload_lds16(gslice + c2 * CHUNK + lane * 8, lbuf + c * CHUNK);
    }
}

// ---- one K-slice of MFMA: A from act LDS, B from staged slice buffer -------
template<int NT>
__device__ __forceinline__ void gemm_slice(const u16* wb, const u16* actw, int koff,
        int lane, int col, f32x4 (&acc)[2][NT])
{
    short8 Af[2];
#pragma unroll
    for (int i = 0; i < 2; ++i)
        Af[i] = *(const short8*)&actw[(i * 16 + col) * SA + koff];
#pragma unroll
    for (int j = 0; j < NT; ++j) {
        const short8 Bf = *(const short8*)&wb[j * CHUNK + lane * 8];
#pragma unroll
        for (int i = 0; i < 2; ++i)
            acc[i][j] = __builtin_amdgcn_mfma_f32_16x16x32_bf16(Af[i], Bf, acc[i][j], 0, 0, 0);
    }
}

// ---- epilogue: bias+relu+bf16, k-permuted in-place store (b128 + b32) ------
__device__ __forceinline__ void epilogue(
    u16* actw, const float* __restrict__ bias,
    int col, int quad, f32x4 (&acc)[2][10])
{
    float bb[10];
#pragma unroll
    for (int j = 0; j < 10; ++j) {
        const int n = j * 16 + col;
        bb[j] = (n < 150) ? bias[n] : 0.f;
    }
#pragma unroll
    for (int i = 0; i < 2; ++i)
#pragma unroll
        for (int r = 0; r < 4; ++r) {
            u16* row = &actw[(i * 16 + quad * 4 + r) * SA];
            short8 pk;
#pragma unroll
            for (int j = 0; j < 8; ++j)
                pk[j] = (short)f2bf(fmaxf(acc[i][j][r] + bb[j], 0.f));
            *(short8*)&row[col * 8] = pk;                          // k' = col*8 + j
            const u16 lo = f2bf(fmaxf(acc[i][8][r] + bb[8], 0.f));
            const u16 hi = f2bf(fmaxf(acc[i][9][r] + bb[9], 0.f));
            *(unsigned*)&row[128 + col * 2] =                      // k' = 128+col*2+(j-8)
                (unsigned)lo | ((unsigned)hi << 16);
        }
}

// ------------------------------- Edge kernel --------------------------------
// 4 waves x 32 edges; act slabs wave-private (no act barriers). Weight slices
// double-buffered in LDS via async global_load_lds; one __syncthreads per
// slice AFTER compute drains the next slice's staging (overlap).
__global__ __launch_bounds__(NTHR, 2) void edge_kernel(
    const float* __restrict__ t, const float* __restrict__ x, const float* __restrict__ Ofx,
    const int* __restrict__ src, const int* __restrict__ tgt,
    const u16* __restrict__ Wt,
    const float* __restrict__ B0, const float* __restrict__ B1, const float* __restrict__ B2,
    const float* __restrict__ B3, const float* __restrict__ B4,
    float* __restrict__ Ep, int n_edges, int copy_mask, size_t copy_elems)
{
    __shared__ __align__(16) u16 act[BLK_E * SA];      // 43008 B
    __shared__ __align__(16) u16 wbuf[2 * BUFSZ];      // 24576 B
    __shared__ int tgt_s[BLK_E];                       // 512 B   -> 2 blocks/CU

    const int tid  = threadIdx.x;
    const int lane = tid & 63;
    const int wv   = tid >> 6;
    const int col  = lane & 15;
    const int quad = lane >> 4;

    const int xcd = (int)(__builtin_amdgcn_s_getreg(6164) & 7u) & copy_mask;
    float* __restrict__ Epc = Ep + (size_t)xcd * copy_elems;

    // ---- gather R' (wave-private rows: wave wv owns edges [wv*32, wv*32+32))
    {
        const int e = wv * 32 + (lane & 31);
        const int half = lane >> 5;
        const long long ge = (long long)blockIdx.x * BLK_E + e;
        const bool valid = ge < n_edges;
        u16* row = &act[e * SA];
        if (half == 0) {
            const int s = valid ? src[ge] : 0;
            const float4 xs = valid ? *(const float4*)&x[(size_t)s * 4] : float4{0, 0, 0, 0};
            const float2 os = valid ? *(const float2*)&Ofx[(size_t)s * 2] : float2{0, 0};
            *(unsigned*)&row[0] = (unsigned)f2bf(xs.x) | ((unsigned)f2bf(xs.y) << 16);
            *(unsigned*)&row[2] = (unsigned)f2bf(xs.z) | ((unsigned)f2bf(xs.w) << 16);
            *(unsigned*)&row[4] = (unsigned)f2bf(os.x) | ((unsigned)f2bf(os.y) << 16);
            *(short8*)&row[16] = short8{0, 0, 0, 0, 0, 0, 0, 0};
        } else {
            const int g = valid ? tgt[ge] : 0;
            const float4 xg = valid ? *(const float4*)&x[(size_t)g * 4] : float4{0, 0, 0, 0};
            const float2 og = valid ? *(const float2*)&Ofx[(size_t)g * 2] : float2{0, 0};
            const float tv = valid ? t[0] : 0.f;
            *(unsigned*)&row[6]  = (unsigned)f2bf(xg.x) | ((unsigned)f2bf(xg.y) << 16);
            *(unsigned*)&row[8]  = (unsigned)f2bf(xg.z) | ((unsigned)f2bf(xg.w) << 16);
            *(unsigned*)&row[10] = (unsigned)f2bf(og.x) | ((unsigned)f2bf(og.y) << 16);
            *(unsigned*)&row[12] = (unsigned)f2bf(tv);     // k=13 zero
            *(unsigned*)&row[14] = 0u;
            *(short8*)&row[24] = short8{0, 0, 0, 0, 0, 0, 0, 0};
            tgt_s[e] = valid ? g : -1;
        }
    }

    u16* actw = act + wv * 32 * SA;     // this wave's private 32 rows
    const float* Bs[4] = {B0, B1, B2, B3};

    // ---- slice pipeline: stage(s+1) -> compute(s) -> barrier (drains s+1) --
    stage_slice(Wt, wbuf, wv, lane);                        // s=0: (L0,ks0)
    __syncthreads();                                        // drain stage(0)

    f32x4 acc[2][10];
    int pb = 0;

    // L0 (1 slice)
    stage_slice(Wt + 1 * WSLOT, wbuf + BUFSZ, wv, lane);    // s=1: (L1,ks0)
#pragma unroll
    for (int i = 0; i < 2; ++i)
#pragma unroll
        for (int j = 0; j < 10; ++j) acc[i][j] = f32x4{0.f, 0.f, 0.f, 0.f};
    gemm_slice<10>(wbuf + pb * BUFSZ, actw, quad * 8, lane, col, acc);
    epilogue(actw, B0, col, quad, acc);
    __syncthreads(); pb ^= 1;

    // L1..L3 (5 slices each)
    for (int l = 1; l <= 3; ++l) {
#pragma unroll
        for (int i = 0; i < 2; ++i)
#pragma unroll
            for (int j = 0; j < 10; ++j) acc[i][j] = f32x4{0.f, 0.f, 0.f, 0.f};
#pragma unroll
        for (int ks = 0; ks < 5; ++ks) {
            const u16* nxt = (ks < 4) ? (Wt + (size_t)l * WSLOT + (ks + 1) * SLICE_G)
                                      : (Wt + (size_t)(l + 1) * WSLOT);
            stage_slice(nxt, wbuf + (pb ^ 1) * BUFSZ, wv, lane);
            gemm_slice<10>(wbuf + pb * BUFSZ, actw, ks * 32 + quad * 8, lane, col, acc);
            if (ks == 4) epilogue(actw, Bs[l], col, quad, acc);
            __syncthreads(); pb ^= 1;
        }
    }

    // L4 (5 slices, NT=4, linear) then scatter
    f32x4 acc4[2][4];
#pragma unroll
    for (int i = 0; i < 2; ++i)
#pragma unroll
        for (int j = 0; j < 4; ++j) acc4[i][j] = f32x4{0.f, 0.f, 0.f, 0.f};
#pragma unroll
    for (int ks = 0; ks < 5; ++ks) {
        if (ks < 4) stage_slice(Wt + 4 * (size_t)WSLOT + (ks + 1) * SLICE_G,
                                wbuf + (pb ^ 1) * BUFSZ, wv, lane);
        gemm_slice<4>(wbuf + pb * BUFSZ, actw, ks * 32 + quad * 8, lane, col, acc4);
        __syncthreads(); pb ^= 1;
    }

    // ---- scatter-add E into XCD-local Ep copy: 4 nodes x 64 B per instr ----
#pragma unroll
    for (int j = 0; j < 4; ++j) {
        const int n = j * 16 + col;
        if (n < 50) {
            const float bb = B4[n];
#pragma unroll
            for (int i = 0; i < 2; ++i)
#pragma unroll
                for (int r = 0; r < 4; ++r) {
                    const int g = tgt_s[wv * 32 + i * 16 + quad * 4 + r];
                    if (g >= 0) atomicAdd(&Epc[(size_t)g * 50 + n], acc4[i][j][r] + bb);
                }
        }
    }
}

// ---------------- Node kernel: reduce copies + fO MLP (fp32 VALU) -----------
template<int DI, int DO, bool RELU>
__device__ __forceinline__ void mlp_layer_t(
    const float* __restrict__ W, const float* __restrict__ B,
    float (*in)[64], float (*out)[64], int tid)
{
    const int et = tid & 15;
    const int jt = tid >> 4;
    constexpr int NG = (DO + 15) / 16;

    float acc0[NG], acc1[NG], acc2[NG], acc3[NG];
#pragma unroll
    for (int g = 0; g < NG; ++g) {
        const int j = jt + 16 * g;
        const float bb = (j < DO) ? B[j] : 0.f;
        acc0[g] = bb; acc1[g] = bb; acc2[g] = bb; acc3[g] = bb;
    }
    for (int k = 0; k < DI; ++k) {
        const float4 a = *(const float4*)&in[k][et * 4];
#pragma unroll
        for (int g = 0; g < NG; ++g) {
            const int j = jt + 16 * g;
            const float wv = (j < DO) ? W[k * DO + j] : 0.f;
            acc0[g] = fmaf(a.x, wv, acc0[g]);
            acc1[g] = fmaf(a.y, wv, acc1[g]);
            acc2[g] = fmaf(a.z, wv, acc2[g]);
            acc3[g] = fmaf(a.w, wv, acc3[g]);
        }
    }
#pragma unroll
    for (int g = 0; g < NG; ++g) {
        const int j = jt + 16 * g;
        if (j < DO) {
            float4 v; v.x = acc0[g]; v.y = acc1[g]; v.z = acc2[g]; v.w = acc3[g];
            if (RELU) {
                v.x = fmaxf(v.x, 0.f); v.y = fmaxf(v.y, 0.f);
                v.z = fmaxf(v.z, 0.f); v.w = fmaxf(v.w, 0.f);
            }
            *(float4*)&out[j][et * 4] = v;
        }
    }
}

__global__ __launch_bounds__(256, 2) void node_kernel(
    const float* __restrict__ Ep, int ncopies, size_t copy_elems,
    const float* __restrict__ W0, const float* __restrict__ B0,
    const float* __restrict__ W1, const float* __restrict__ B1,
    float* __restrict__ P, int n_nodes)
{
    __shared__ float bufA[104][64];
    __shared__ float bufB[104][64];
    const int tid = threadIdx.x;
    const int n0  = blockIdx.x * 64;

    for (int idx = tid; idx < 64 * 50; idx += 256) {
        const int e = idx / 50;
        const int k = idx - e * 50;
        const int n = n0 + e;
        float s = 0.f;
        if (n < n_nodes) {
            const float* p = &Ep[(size_t)n * 50 + k];
            for (int c = 0; c < ncopies; ++c) s += p[(size_t)c * copy_elems];
        }
        bufA[k][e] = s;
    }
    __syncthreads();
    mlp_layer_t<50, 100, true >(W0, B0, bufA, bufB, tid); __syncthreads();
    mlp_layer_t<100, 4, false>(W1, B1, bufB, bufA, tid); __syncthreads();
    for (int idx = tid; idx < 64 * 4; idx += 256) {
        const int e = idx & 63;
        const int j = idx >> 6;
        const int n = n0 + e;
        if (n < n_nodes) P[(size_t)n * 4 + j] = bufA[j][e];
    }
}

// ------------------------------- launcher -----------------------------------
extern "C" void kernel_launch(void* const* d_in, const int* in_sizes, int n_in,
                              void* d_out, int out_size, void* d_ws, size_t ws_size,
                              hipStream_t stream)
{
    const float* t   = (const float*)d_in[0];
    const float* x   = (const float*)d_in[1];
    const float* Ofx = (const float*)d_in[2];
    const int*   src = (const int*)d_in[3];
    const int*   tgt = (const int*)d_in[4];
    const float* W0  = (const float*)d_in[5];  const float* B0 = (const float*)d_in[6];
    const float* W1  = (const float*)d_in[7];  const float* B1 = (const float*)d_in[8];
    const float* W2  = (const float*)d_in[9];  const float* B2 = (const float*)d_in[10];
    const float* W3  = (const float*)d_in[11]; const float* B3 = (const float*)d_in[12];
    const float* W4  = (const float*)d_in[13]; const float* B4 = (const float*)d_in[14];
    const float* OW0 = (const float*)d_in[15]; const float* OB0 = (const float*)d_in[16];
    const float* OW1 = (const float*)d_in[17]; const float* OB1 = (const float*)d_in[18];

    const int n_nodes = in_sizes[1] / 4;
    const int n_edges = in_sizes[3];

    u16*   Wt = (u16*)d_ws;                                // 5*51200 = 256000 B
    float* Ep = (float*)((char*)d_ws + 262144);            // ncopies x [N,50] fp32

    const size_t copy_elems = (size_t)n_nodes * 50;
    const size_t avail = (ws_size > 262144) ? ws_size - 262144 : 0;
    int ncopies = 1;                                        // power of two, <= 4
    while (ncopies * 2 <= 4 &&
           (size_t)(ncopies * 2) * copy_elems * sizeof(float) <= avail)
        ncopies *= 2;
    const int copy_mask = ncopies - 1;

    prep_weights<<<dim3(32, 5), 256, 0, stream>>>(W0, W1, W2, W3, W4, Wt);
    hipMemsetAsync(Ep, 0, (size_t)ncopies * copy_elems * sizeof(float), stream);

    edge_kernel<<<(n_edges + BLK_E - 1) / BLK_E, NTHR, 0, stream>>>(
        t, x, Ofx, src, tgt, Wt, B0, B1, B2, B3, B4,
        Ep, n_edges, copy_mask, copy_elems);

    node_kernel<<<(n_nodes + 63) / 64, 256, 0, stream>>>(
        Ep, ncopies, copy_elems, OW0, OB0, OW1, OB1, (float*)d_out, n_nodes);
}